// Round 8
// baseline (21.435 us; speedup 1.0000x reference)
//
#include <hip/hip_runtime.h>

// 3x3 median filter, reflect padding, fp32, NCHW (4,3,1024,1024).
// 256 threads = full 1024-wide row (4 px/thread as float4); each block
// computes R=8 rows (1536 blocks -> 6 blocks/CU), software-pipelined
// (issue row r+2 / finalize row r+1 / compute row r).
// THIS ROUND: register-pressure fix. __launch_bounds__(256,6) caps VGPR
// at ~85 so all 6 blocks/CU (24 waves/CU) are co-resident, and the median
// is computed with a sliding 3-column (lo,mi,hi) window (9 live regs
// instead of 22) so the cap is met without spilling.
// Median-of-9 = column decomposition: med3(max3(lo), med3(mi), min3(hi)).

constexpr int R = 8;
constexpr int NXCD = 8;

__device__ __forceinline__ float med3(float a, float b, float c) {
  return __builtin_amdgcn_fmed3f(a, b, c);
}

struct Raw { float4 m; float lh, rh; };

__global__ __launch_bounds__(256, 6) void median3x3_kernel(
    const float* __restrict__ in, float* __restrict__ out, int H, int W,
    int tiles_per_plane, int chunk) {
  const int wg  = blockIdx.x;
  const int swz = (wg & (NXCD - 1)) * chunk + (wg >> 3);
  const int plane = swz / tiles_per_plane;
  const int y0    = (swz % tiles_per_plane) * R;

  const int tid  = threadIdx.x;
  const int x0   = tid * 4;
  const int lane = tid & 63;
  const bool ledge = (x0 == 0);          // reflect col -1 -> 1  (= m.y)
  const bool redge = (x0 + 4 >= W);      // reflect col W  -> W-2 (= m.z)

  const float* p = in  + (size_t)plane * H * W;
  float*       q = out + (size_t)plane * H * W;

  // ISSUE: start loads for row y; no use of the results here.
  auto issue = [&](int y, Raw& rw) {
    const float* rp = p + (size_t)y * W;
    rw.m = *reinterpret_cast<const float4*>(rp + x0);
    if (lane == 0 && !ledge)  rw.lh = rp[x0 - 1];   // cross-wave halo
    if (lane == 63 && !redge) rw.rh = rp[x0 + 4];
  };

  // FINALIZE: shuffles + halo select (vmcnt wait lands here).
  auto finalize = [&](const Raw& rw, float (&v)[6]) {
    float lh = __shfl_up(rw.m.w, 1);
    float rh = __shfl_down(rw.m.x, 1);
    if (lane == 0)  lh = ledge ? rw.m.y : rw.lh;
    if (lane == 63) rh = redge ? rw.m.z : rw.rh;
    v[0] = lh; v[1] = rw.m.x; v[2] = rw.m.y; v[3] = rw.m.z; v[4] = rw.m.w; v[5] = rh;
  };

  float v[3][6];
  Raw raw[2];

  // prime: rows ym (reflect -1 -> 1), y0, y0+1
  issue(y0 == 0 ? 1 : y0 - 1, raw[0]);
  issue(y0, raw[1]);
  finalize(raw[0], v[0]);
  finalize(raw[1], v[1]);
  issue(y0 + 1, raw[1]);            // consumed at iter 0's finalize

  #pragma unroll
  for (int r = 0; r < R; ++r) {
    if (r < R - 1) {                // issue row r+2 (consumed at iter r+1)
      int y2 = y0 + r + 2;
      y2 = (y2 >= H) ? 2 * H - 2 - y2 : y2;   // reflect: H -> H-2
      issue(y2, raw[r & 1]);
    }
    finalize(raw[(r + 1) & 1], v[(r + 2) % 3]);  // row r+1, issued at r-1

    const float (&a)[6] = v[r % 3];
    const float (&b)[6] = v[(r + 1) % 3];
    const float (&c)[6] = v[(r + 2) % 3];

    // sliding 3-column window: per column j compute sorted vertical triple
    // (lo,mi,hi); once 3 columns are live, emit output i = j-2.
    float lo[3], mi[3], hi[3];
    float4 o;
    float* op = &o.x;
    #pragma unroll
    for (int j = 0; j < 6; ++j) {
      const float aj = a[j], bj = b[j], cj = c[j];
      const float plo = fminf(bj, cj);
      const float phi = fmaxf(bj, cj);
      lo[j % 3] = fminf(aj, plo);
      hi[j % 3] = fmaxf(aj, phi);
      mi[j % 3] = fmaxf(plo, fminf(aj, phi));
      if (j >= 2) {
        const float mxlo = fmaxf(fmaxf(lo[0], lo[1]), lo[2]);
        const float mnhi = fminf(fminf(hi[0], hi[1]), hi[2]);
        const float mdmi = med3(mi[0], mi[1], mi[2]);
        op[j - 2] = med3(mxlo, mdmi, mnhi);
      }
    }
    *reinterpret_cast<float4*>(q + (size_t)(y0 + r) * W + x0) = o;
  }
}

extern "C" void kernel_launch(void* const* d_in, const int* in_sizes, int n_in,
                              void* d_out, int out_size, void* d_ws, size_t ws_size,
                              hipStream_t stream) {
  const float* x = (const float*)d_in[0];
  float* out = (float*)d_out;

  const int H = 1024, W = 1024;
  const int planes = in_sizes[0] / (H * W);      // B*C = 12
  const int tiles_per_plane = H / R;             // 128
  const int nblocks = planes * tiles_per_plane;  // 1536 (divisible by 8)
  const int chunk = nblocks / NXCD;              // 192

  dim3 grid(nblocks);
  dim3 block(W / 4);  // 256 threads, 4 px each
  median3x3_kernel<<<grid, block, 0, stream>>>(x, out, H, W,
                                               tiles_per_plane, chunk);
}